// Round 1
// baseline (525.167 us; speedup 1.0000x reference)
//
#include <hip/hip_runtime.h>

// MaskedAttention: B=4, NQ=1024, HW=4096, C=1024, H=8, DH=128
// Pipeline: cvt(f32->bf16) -> maskbits -> GEMM Q/K/V (bf16 MFMA) -> flash attn -> GEMM O (f32 out)

#define NB 4
#define NQL 1024
#define HWK 4096
#define CC 1024
#define NH 8
#define DHD 128

typedef __attribute__((ext_vector_type(8))) short s16x8;
typedef __attribute__((ext_vector_type(4))) short s16x4;
typedef __attribute__((ext_vector_type(4))) float f32x4;
typedef unsigned int u32;
typedef unsigned long long u64;
typedef const __attribute__((address_space(1))) u32* gas1;
typedef __attribute__((address_space(3))) u32* las3;

__device__ __forceinline__ unsigned short f2bf(float f) {
  u32 u = __float_as_uint(f);
  u32 r = u + 0x7FFFu + ((u >> 16) & 1u);   // RNE
  return (unsigned short)(r >> 16);
}

__device__ __forceinline__ void gld16(const void* g, void* l) {
  __builtin_amdgcn_global_load_lds((gas1)g, (las3)l, 16, 0, 0);
}

#define MFMA16(a, b, c) __builtin_amdgcn_mfma_f32_16x16x32_bf16((a), (b), (c), 0, 0, 0)

// ---------------- f32 -> bf16 (RNE), 8 elems/thread ----------------
__global__ void cvt_bf16(const float* __restrict__ s, short* __restrict__ d, int n8) {
  int i = blockIdx.x * 256 + threadIdx.x;
  int stride = gridDim.x * 256;
  for (; i < n8; i += stride) {
    const float4* s4 = (const float4*)s;
    float4 a = s4[i * 2];
    float4 b = s4[i * 2 + 1];
    s16x8 o;
    o[0] = (short)f2bf(a.x); o[1] = (short)f2bf(a.y);
    o[2] = (short)f2bf(a.z); o[3] = (short)f2bf(a.w);
    o[4] = (short)f2bf(b.x); o[5] = (short)f2bf(b.y);
    o[6] = (short)f2bf(b.z); o[7] = (short)f2bf(b.w);
    *(s16x8*)(d + (size_t)i * 8) = o;
  }
}

// ---------------- mask -> permuted bitmask words ----------------
// storage bit p (p = hi*16 + nf*4 + r) holds allowed(k = nf*16 + hi*4 + r)
__global__ void mask_bits(const float* __restrict__ mask, u64* __restrict__ words) {
  int t = blockIdx.x * 256 + threadIdx.x;
  int wi = t >> 6;
  int lane = t & 63;
  int k = ((lane >> 2) & 3) * 16 + (lane >> 4) * 4 + (lane & 3);
  float v = mask[(size_t)wi * 64 + k];
  u64 bits = __ballot(v >= 0.5f);
  if (lane == 0) words[wi] = bits;
}

// ---------------- GEMM: C[M,N] = A[M,K] @ W[N,K]^T + bias ; N=K=1024 ----------------
// m97 structure: 128x128 tile, BK=32, 4 waves (each 64x64 = 4x4 16x16x32 frags),
// global_load_lds(16B) staging with XOR-swizzled LDS (source pre-swizzle).
// EPI: 0 = bf16 out, (acc+bias)*scale   (Q-proj, scale folds 1/sqrt(dh)*log2e)
//      1 = bf16 out, acc+bias           (K-proj)
//      2 = bf16 out transposed to [B,H,DH,HW]  (V-proj)
//      3 = f32 out, acc+bias            (O-proj -> d_out)
template <int EPI>
__global__ __launch_bounds__(256, 2) void gemm_bt(const short* __restrict__ A,
                                                  const short* __restrict__ W,
                                                  const float* __restrict__ bias,
                                                  void* __restrict__ Cout, float scale) {
  __shared__ alignas(16) short As[128 * 32];
  __shared__ alignas(16) short Bs[128 * 32];
  int nwg = gridDim.x;
  int bid = blockIdx.x;
  int wg = (bid & 7) * (nwg >> 3) + (bid >> 3);   // bijective XCD swizzle (nwg%8==0)
  int bm = wg >> 3;
  int bn = wg & 7;
  int tid = threadIdx.x;
  int w = tid >> 6, lane = tid & 63, lo = lane & 15, hi = lane >> 4;
  int wr = w >> 1, wc = w & 1;
  const short* Ab = A + (size_t)bm * 128 * 1024;
  const short* Wb = W + (size_t)bn * 128 * 1024;
  f32x4 acc[4][4] = {};
  int srow = lane >> 2;             // row within 16-row chunk
  int scolb = (lane & 3) * 16;      // byte col within 64B row

  for (int kt = 0; kt < 32; ++kt) {
    __syncthreads();
#pragma unroll
    for (int i = 0; i < 2; ++i) {
      int c = w * 2 + i;
      int row = c * 16 + srow;
      int sc = scolb ^ ((row & 3) << 4);   // pre-swizzle source so swizzled LDS is linear-dest
      gld16(Ab + (size_t)row * 1024 + kt * 32 + (sc >> 1), (char*)As + c * 1024);
      gld16(Wb + (size_t)row * 1024 + kt * 32 + (sc >> 1), (char*)Bs + c * 1024);
    }
    __syncthreads();
    s16x8 af[4], bf[4];
#pragma unroll
    for (int mf = 0; mf < 4; ++mf) {
      int row = wr * 64 + mf * 16 + lo;
      af[mf] = *(const s16x8*)((const char*)As + row * 64 + ((hi * 16) ^ ((row & 3) << 4)));
    }
#pragma unroll
    for (int nf = 0; nf < 4; ++nf) {
      int row = wc * 64 + nf * 16 + lo;
      bf[nf] = *(const s16x8*)((const char*)Bs + row * 64 + ((hi * 16) ^ ((row & 3) << 4)));
    }
#pragma unroll
    for (int mf = 0; mf < 4; ++mf)
#pragma unroll
      for (int nf = 0; nf < 4; ++nf) acc[mf][nf] = MFMA16(af[mf], bf[nf], acc[mf][nf]);
  }

  // epilogue: C/D layout col=lane&15, row=(lane>>4)*4+reg
#pragma unroll
  for (int nf = 0; nf < 4; ++nf) {
    int n = bn * 128 + wc * 64 + nf * 16 + lo;
    float bv = bias[n];
#pragma unroll
    for (int mf = 0; mf < 4; ++mf) {
      int m0 = bm * 128 + wr * 64 + mf * 16 + hi * 4;
      if constexpr (EPI == 0 || EPI == 1) {
        short* O = (short*)Cout;
#pragma unroll
        for (int r = 0; r < 4; ++r) {
          float v = acc[mf][nf][r] + bv;
          if constexpr (EPI == 0) v *= scale;
          O[(size_t)(m0 + r) * 1024 + n] = (short)f2bf(v);
        }
      } else if constexpr (EPI == 2) {
        short* O = (short*)Cout;
        int bb = m0 >> 12;       // batch (HW=4096 rows per batch)
        int kk = m0 & 4095;      // key index
        s16x4 pk;
#pragma unroll
        for (int r = 0; r < 4; ++r) pk[r] = (short)f2bf(acc[mf][nf][r] + bv);
        *(s16x4*)(O + (size_t)bb * 4194304 + (size_t)n * 4096 + kk) = pk;
      } else {
        float* O = (float*)Cout;
#pragma unroll
        for (int r = 0; r < 4; ++r) O[(size_t)(m0 + r) * 1024 + n] = acc[mf][nf][r] + bv;
      }
    }
  }
}

// ---------------- flash attention ----------------
// grid 256: wg = bh*8 + qb (XCD-swizzled). Block = 4 waves, each owns 32 q-rows.
// KVBLK=64, K/V double-buffered LDS (XOR swizzle via pre-swizzled global src).
// Swapped QK^T: S^T = mfma(K_frag, Q_frag) -> lane holds S^T[k][q=lane&15].
// Q pre-scaled by (1/sqrt(128))*log2e so softmax = exp2.
__global__ __launch_bounds__(256, 1) void attn_kernel(const short* __restrict__ Qp,
                                                      const short* __restrict__ Kp,
                                                      const short* __restrict__ VT,
                                                      const u64* __restrict__ Mb,
                                                      short* __restrict__ AO) {
  __shared__ alignas(16) short Ks[2][8192];   // [64 k][128 d] swizzled
  __shared__ alignas(16) short Vs[2][8192];   // [128 d][64 k] swizzled (from V^T global)
  __shared__ alignas(16) short Ps[4][2048];   // per-wave [32 q][64 k] swizzled

  int bid = blockIdx.x;
  int wg = (bid & 7) * 32 + (bid >> 3);
  int bh = wg >> 3, qb = wg & 7;
  int b = bh >> 3, h = bh & 7;
  int tid = threadIdx.x, w = tid >> 6, lane = tid & 63, lo = lane & 15, hi = lane >> 4;
  int q0 = qb * 128 + w * 32;

  // Q fragments: lane holds Q[q][dk = kf*32 + hi*8 + i]
  s16x8 qf_[2][4];
#pragma unroll
  for (int qf = 0; qf < 2; ++qf)
#pragma unroll
    for (int kf = 0; kf < 4; ++kf) {
      int q = q0 + qf * 16 + lo;
      qf_[qf][kf] = *(const s16x8*)(Qp + (size_t)(b * NQL + q) * CC + h * DHD + kf * 32 + hi * 8);
    }

  f32x4 acc[2][8] = {};
  float m_[2] = {-3e38f, -3e38f};
  float l_[2] = {0.f, 0.f};

  int krow = lane >> 4;            // 0..3   (K: 16 lanes/row of 256B)
  int kcolb = (lane & 15) * 16;
  int vrow = lane >> 3;            // 0..7   (V: 8 lanes/row of 128B)
  int vcolb = (lane & 7) * 16;

  auto stage = [&](int t, int buf) {
    int kv0 = t * 64;
#pragma unroll
    for (int i = 0; i < 4; ++i) {
      int c = w * 4 + i;
      int row = c * 4 + krow;
      int sc = kcolb ^ ((row & 7) << 4);
      gld16(Kp + (size_t)(b * HWK + kv0 + row) * CC + h * DHD + (sc >> 1), (char*)Ks[buf] + c * 1024);
    }
#pragma unroll
    for (int i = 0; i < 4; ++i) {
      int c = w * 4 + i;
      int d = c * 8 + vrow;
      int sc = vcolb ^ ((d & 7) << 4);
      gld16(VT + (size_t)((b * NH + h) * DHD + d) * HWK + kv0 + (sc >> 1), (char*)Vs[buf] + c * 1024);
    }
  };

  stage(0, 0);
  __syncthreads();

  for (int t = 0; t < 64; ++t) {
    int buf = t & 1;
    if (t < 63) stage(t + 1, buf ^ 1);   // prefetch: drains at end-of-iter barrier

    // ---- S^T = K @ Q^T ----
    f32x4 st[2][4] = {};
#pragma unroll
    for (int nf = 0; nf < 4; ++nf) {
      int kidx = nf * 16 + lo;
      int swz = (kidx & 7) << 4;
#pragma unroll
      for (int kf = 0; kf < 4; ++kf) {
        s16x8 a = *(const s16x8*)((const char*)Ks[buf] + kidx * 256 + ((kf * 64 + hi * 16) ^ swz));
        st[0][nf] = MFMA16(a, qf_[0][kf], st[0][nf]);
        st[1][nf] = MFMA16(a, qf_[1][kf], st[1][nf]);
      }
    }

    // ---- online softmax (wave-parallel; state per q=lane&15, replicated over hi) ----
#pragma unroll
    for (int qf = 0; qf < 2; ++qf) {
      int q = q0 + qf * 16 + lo;
      u64 word = Mb[(size_t)(b * NQL + q) * 64 + t];
      u32 halfm = (u32)(word >> (hi * 16)) & 0xFFFFu;
      float smax = -3e38f;
#pragma unroll
      for (int nf = 0; nf < 4; ++nf)
#pragma unroll
        for (int r = 0; r < 4; ++r) smax = fmaxf(smax, st[qf][nf][r]);
      smax = fmaxf(smax, __shfl_xor(smax, 16));
      smax = fmaxf(smax, __shfl_xor(smax, 32));
      float mnew = fmaxf(m_[qf], smax);
      float alpha = __builtin_amdgcn_exp2f(m_[qf] - mnew);
      float tsum = 0.f;
      int qr = qf * 16 + lo;
#pragma unroll
      for (int nf = 0; nf < 4; ++nf) {
        float p0 = __builtin_amdgcn_exp2f(st[qf][nf][0] - mnew);
        float p1 = __builtin_amdgcn_exp2f(st[qf][nf][1] - mnew);
        float p2 = __builtin_amdgcn_exp2f(st[qf][nf][2] - mnew);
        float p3 = __builtin_amdgcn_exp2f(st[qf][nf][3] - mnew);
        p0 = ((halfm >> (nf * 4 + 0)) & 1) ? p0 : 0.f;
        p1 = ((halfm >> (nf * 4 + 1)) & 1) ? p1 : 0.f;
        p2 = ((halfm >> (nf * 4 + 2)) & 1) ? p2 : 0.f;
        p3 = ((halfm >> (nf * 4 + 3)) & 1) ? p3 : 0.f;
        tsum += p0 + p1 + p2 + p3;
        u32 w0 = __builtin_amdgcn_perm(__float_as_uint(p1), __float_as_uint(p0), 0x07060302u);
        u32 w1 = __builtin_amdgcn_perm(__float_as_uint(p3), __float_as_uint(p2), 0x07060302u);
        uint2 pv; pv.x = w0; pv.y = w1;
        *(uint2*)((char*)Ps[w] + qr * 128 + ((nf * 32 + hi * 8) ^ ((lo & 7) << 4))) = pv;
      }
      tsum += __shfl_xor(tsum, 16);
      tsum += __shfl_xor(tsum, 32);
      l_[qf] = l_[qf] * alpha + tsum;
      m_[qf] = mnew;
      float ar0 = __shfl(alpha, hi * 4 + 0);
      float ar1 = __shfl(alpha, hi * 4 + 1);
      float ar2 = __shfl(alpha, hi * 4 + 2);
      float ar3 = __shfl(alpha, hi * 4 + 3);
#pragma unroll
      for (int df = 0; df < 8; ++df) {
        acc[qf][df][0] *= ar0; acc[qf][df][1] *= ar1;
        acc[qf][df][2] *= ar2; acc[qf][df][3] *= ar3;
      }
    }
    asm volatile("" ::: "memory");   // keep P ds_writes before P ds_reads (alias fence)

    // ---- PV: acc[q][d] += P @ V ----
#pragma unroll
    for (int kt = 0; kt < 2; ++kt) {
      s16x8 pa0 = *(const s16x8*)((const char*)Ps[w] + (0 + lo) * 128 + ((kt * 64 + hi * 16) ^ ((lo & 7) << 4)));
      s16x8 pa1 = *(const s16x8*)((const char*)Ps[w] + (16 + lo) * 128 + ((kt * 64 + hi * 16) ^ ((lo & 7) << 4)));
#pragma unroll
      for (int df = 0; df < 8; ++df) {
        int d = df * 16 + lo;
        s16x8 vb = *(const s16x8*)((const char*)Vs[buf] + d * 128 + ((kt * 64 + hi * 16) ^ ((lo & 7) << 4)));
        acc[0][df] = MFMA16(pa0, vb, acc[0][df]);
        acc[1][df] = MFMA16(pa1, vb, acc[1][df]);
      }
    }
    __syncthreads();
  }

  // ---- epilogue: out = acc / l -> bf16 AO[B,NQ,C] ----
#pragma unroll
  for (int qf = 0; qf < 2; ++qf) {
    float linv = 1.0f / l_[qf];
    float lr0 = __shfl(linv, hi * 4 + 0);
    float lr1 = __shfl(linv, hi * 4 + 1);
    float lr2 = __shfl(linv, hi * 4 + 2);
    float lr3 = __shfl(linv, hi * 4 + 3);
    int qbase = q0 + qf * 16 + hi * 4;
#pragma unroll
    for (int df = 0; df < 8; ++df) {
      int col = h * DHD + df * 16 + lo;
      AO[(size_t)(b * NQL + qbase + 0) * CC + col] = (short)f2bf(acc[qf][df][0] * lr0);
      AO[(size_t)(b * NQL + qbase + 1) * CC + col] = (short)f2bf(acc[qf][df][1] * lr1);
      AO[(size_t)(b * NQL + qbase + 2) * CC + col] = (short)f2bf(acc[qf][df][2] * lr2);
      AO[(size_t)(b * NQL + qbase + 3) * CC + col] = (short)f2bf(acc[qf][df][3] * lr3);
    }
  }
}

// ---------------- launcher ----------------
extern "C" void kernel_launch(void* const* d_in, const int* in_sizes, int n_in,
                              void* d_out, int out_size, void* d_ws, size_t ws_size,
                              hipStream_t stream) {
  (void)in_sizes; (void)n_in; (void)out_size; (void)ws_size;
  const float* query = (const float*)d_in[0];
  const float* memory = (const float*)d_in[1];
  const float* mask = (const float*)d_in[2];
  const float* Wq = (const float*)d_in[3];
  const float* bq = (const float*)d_in[4];
  const float* Wk = (const float*)d_in[5];
  const float* bk = (const float*)d_in[6];
  const float* Wv = (const float*)d_in[7];
  const float* bv = (const float*)d_in[8];
  const float* Wo = (const float*)d_in[9];
  const float* bo = (const float*)d_in[10];
  float* out = (float*)d_out;

  char* ws = (char*)d_ws;
  short* qbf = (short*)(ws);                      // 8MB  query bf16
  short* mbf = (short*)(ws + (8ull << 20));       // 32MB memory bf16
  short* wqb = (short*)(ws + (40ull << 20));      // 2MB each: Wq,Wk,Wv,Wo bf16
  short* wkb = wqb + (1u << 20);
  short* wvb = wqb + (2u << 20);
  short* wob = wqb + (3u << 20);
  u64* mbits = (u64*)(ws + (48ull << 20));        // 2MB mask bits
  short* Qp = (short*)(ws + (50ull << 20));       // 8MB  Q proj  [B,NQ,C]
  short* Kp = (short*)(ws + (58ull << 20));       // 32MB K proj  [B,HW,C]
  short* VT = (short*)(ws + (90ull << 20));       // 32MB V proj  [B,H,DH,HW]
  short* AO = (short*)(ws + (122ull << 20));      // 8MB  attn out [B,NQ,C]

  cvt_bf16<<<2048, 256, 0, stream>>>(query, qbf, (NB * NQL * CC) / 8);
  cvt_bf16<<<2048, 256, 0, stream>>>(memory, mbf, (NB * HWK * CC) / 8);
  cvt_bf16<<<512, 256, 0, stream>>>(Wq, wqb, (CC * CC) / 8);
  cvt_bf16<<<512, 256, 0, stream>>>(Wk, wkb, (CC * CC) / 8);
  cvt_bf16<<<512, 256, 0, stream>>>(Wv, wvb, (CC * CC) / 8);
  cvt_bf16<<<512, 256, 0, stream>>>(Wo, wob, (CC * CC) / 8);
  mask_bits<<<65536, 256, 0, stream>>>(mask, mbits);

  const float qscale = 0.08838834764831845f * 1.4426950408889634f;  // 1/sqrt(128) * log2(e)
  gemm_bt<0><<<256, 256, 0, stream>>>(qbf, wqb, bq, Qp, qscale);
  gemm_bt<1><<<1024, 256, 0, stream>>>(mbf, wkb, bk, Kp, 1.0f);
  gemm_bt<2><<<1024, 256, 0, stream>>>(mbf, wvb, bv, VT, 1.0f);
  attn_kernel<<<256, 256, 0, stream>>>(Qp, Kp, VT, mbits, AO);
  gemm_bt<3><<<256, 256, 0, stream>>>(AO, wob, bo, out, 1.0f);
}

// Round 2
// 459.426 us; speedup vs baseline: 1.1431x; 1.1431x over previous
//
#include <hip/hip_runtime.h>

// MaskedAttention: B=4, NQ=1024, HW=4096, C=1024, H=8, DH=128
// Pipeline: cvt(f32->bf16) -> maskbits -> GEMM Q/K/V (bf16 MFMA) -> flash attn -> GEMM O (f32 out)

#define NB 4
#define NQL 1024
#define HWK 4096
#define CC 1024
#define NH 8
#define DHD 128

typedef __attribute__((ext_vector_type(8))) short s16x8;
typedef __attribute__((ext_vector_type(4))) short s16x4;
typedef __attribute__((ext_vector_type(4))) float f32x4;
typedef unsigned int u32;
typedef unsigned long long u64;
typedef const __attribute__((address_space(1))) u32* gas1;
typedef __attribute__((address_space(3))) u32* las3;

__device__ __forceinline__ unsigned short f2bf(float f) {
  u32 u = __float_as_uint(f);
  u32 r = u + 0x7FFFu + ((u >> 16) & 1u);   // RNE
  return (unsigned short)(r >> 16);
}

__device__ __forceinline__ void gld16(const void* g, void* l) {
  __builtin_amdgcn_global_load_lds((gas1)g, (las3)l, 16, 0, 0);
}

#define MFMA16(a, b, c) __builtin_amdgcn_mfma_f32_16x16x32_bf16((a), (b), (c), 0, 0, 0)

// ---------------- f32 -> bf16 (RNE), 8 elems/thread ----------------
__global__ void cvt_bf16(const float* __restrict__ s, short* __restrict__ d, int n8) {
  int i = blockIdx.x * 256 + threadIdx.x;
  int stride = gridDim.x * 256;
  for (; i < n8; i += stride) {
    const float4* s4 = (const float4*)s;
    float4 a = s4[i * 2];
    float4 b = s4[i * 2 + 1];
    s16x8 o;
    o[0] = (short)f2bf(a.x); o[1] = (short)f2bf(a.y);
    o[2] = (short)f2bf(a.z); o[3] = (short)f2bf(a.w);
    o[4] = (short)f2bf(b.x); o[5] = (short)f2bf(b.y);
    o[6] = (short)f2bf(b.z); o[7] = (short)f2bf(b.w);
    *(s16x8*)(d + (size_t)i * 8) = o;
  }
}

// ---------------- mask -> permuted bitmask words ----------------
// storage bit p (p = hi*16 + nf*4 + r) holds allowed(k = nf*16 + hi*4 + r)
__global__ void mask_bits(const float* __restrict__ mask, u64* __restrict__ words) {
  int t = blockIdx.x * 256 + threadIdx.x;
  int wi = t >> 6;
  int lane = t & 63;
  int k = ((lane >> 2) & 3) * 16 + (lane >> 4) * 4 + (lane & 3);
  float v = mask[(size_t)wi * 64 + k];
  u64 bits = __ballot(v >= 0.5f);
  if (lane == 0) words[wi] = bits;
}

// ---------------- GEMM: C[M,N] = A[M,K] @ W[N,K]^T + bias ; N=K=1024 ----------------
// m97 structure: 128x128 tile, BK=32, 4 waves (each 64x64 = 4x4 16x16x32 frags),
// global_load_lds(16B) staging with XOR-swizzled LDS (source pre-swizzle).
// EPI: 0 = bf16 out, (acc+bias)*scale   (Q-proj, scale folds 1/sqrt(dh)*log2e)
//      1 = bf16 out, acc+bias           (K-proj)
//      2 = bf16 out transposed to [B,H,DH,HW]  (V-proj)
//      3 = f32 out, acc+bias            (O-proj -> d_out)
template <int EPI>
__global__ __launch_bounds__(256, 2) void gemm_bt(const short* __restrict__ A,
                                                  const short* __restrict__ W,
                                                  const float* __restrict__ bias,
                                                  void* __restrict__ Cout, float scale) {
  __shared__ alignas(16) short As[128 * 32];
  __shared__ alignas(16) short Bs[128 * 32];
  int nwg = gridDim.x;
  int bid = blockIdx.x;
  int wg = (bid & 7) * (nwg >> 3) + (bid >> 3);   // bijective XCD swizzle (nwg%8==0)
  int bm = wg >> 3;
  int bn = wg & 7;
  int tid = threadIdx.x;
  int w = tid >> 6, lane = tid & 63, lo = lane & 15, hi = lane >> 4;
  int wr = w >> 1, wc = w & 1;
  const short* Ab = A + (size_t)bm * 128 * 1024;
  const short* Wb = W + (size_t)bn * 128 * 1024;
  f32x4 acc[4][4] = {};
  int srow = lane >> 2;             // row within 16-row chunk
  int scolb = (lane & 3) * 16;      // byte col within 64B row

  for (int kt = 0; kt < 32; ++kt) {
    __syncthreads();
#pragma unroll
    for (int i = 0; i < 2; ++i) {
      int c = w * 2 + i;
      int row = c * 16 + srow;
      int sc = scolb ^ ((row & 3) << 4);   // pre-swizzle source so swizzled LDS is linear-dest
      gld16(Ab + (size_t)row * 1024 + kt * 32 + (sc >> 1), (char*)As + c * 1024);
      gld16(Wb + (size_t)row * 1024 + kt * 32 + (sc >> 1), (char*)Bs + c * 1024);
    }
    __syncthreads();
    s16x8 af[4], bf[4];
#pragma unroll
    for (int mf = 0; mf < 4; ++mf) {
      int row = wr * 64 + mf * 16 + lo;
      af[mf] = *(const s16x8*)((const char*)As + row * 64 + ((hi * 16) ^ ((row & 3) << 4)));
    }
#pragma unroll
    for (int nf = 0; nf < 4; ++nf) {
      int row = wc * 64 + nf * 16 + lo;
      bf[nf] = *(const s16x8*)((const char*)Bs + row * 64 + ((hi * 16) ^ ((row & 3) << 4)));
    }
#pragma unroll
    for (int mf = 0; mf < 4; ++mf)
#pragma unroll
      for (int nf = 0; nf < 4; ++nf) acc[mf][nf] = MFMA16(af[mf], bf[nf], acc[mf][nf]);
  }

  // epilogue: C/D layout col=lane&15, row=(lane>>4)*4+reg
#pragma unroll
  for (int nf = 0; nf < 4; ++nf) {
    int n = bn * 128 + wc * 64 + nf * 16 + lo;
    float bv = bias[n];
#pragma unroll
    for (int mf = 0; mf < 4; ++mf) {
      int m0 = bm * 128 + wr * 64 + mf * 16 + hi * 4;
      if constexpr (EPI == 0 || EPI == 1) {
        short* O = (short*)Cout;
#pragma unroll
        for (int r = 0; r < 4; ++r) {
          float v = acc[mf][nf][r] + bv;
          if constexpr (EPI == 0) v *= scale;
          O[(size_t)(m0 + r) * 1024 + n] = (short)f2bf(v);
        }
      } else if constexpr (EPI == 2) {
        short* O = (short*)Cout;
        int bb = m0 >> 12;       // batch (HW=4096 rows per batch)
        int kk = m0 & 4095;      // key index
        s16x4 pk;
#pragma unroll
        for (int r = 0; r < 4; ++r) pk[r] = (short)f2bf(acc[mf][nf][r] + bv);
        *(s16x4*)(O + (size_t)bb * 4194304 + (size_t)n * 4096 + kk) = pk;
      } else {
        float* O = (float*)Cout;
#pragma unroll
        for (int r = 0; r < 4; ++r) O[(size_t)(m0 + r) * 1024 + n] = acc[mf][nf][r] + bv;
      }
    }
  }
}

// ---------------- flash attention ----------------
// grid 512: wg = bh*16 + qb (XCD-swizzled). Block = 4 waves, each owns 16 q-rows.
// -> 2 blocks/CU (LDS 72KB, VGPR<=128): one block's MFMA overlaps the other's softmax.
// KVBLK=64, K/V double-buffered LDS (XOR swizzle via pre-swizzled global src).
// Swapped QK^T: S^T = mfma(K_frag, Q_frag) -> lane holds S^T[k][q=lane&15].
// Q pre-scaled by (1/sqrt(128))*log2e so softmax = exp2.
// Defer-rescale (T13): skip acc rescale unless tile max exceeds running max by >8 (exp2 dom).
__global__ __launch_bounds__(256, 2) void attn_kernel(const short* __restrict__ Qp,
                                                      const short* __restrict__ Kp,
                                                      const short* __restrict__ VT,
                                                      const u64* __restrict__ Mb,
                                                      short* __restrict__ AO) {
  __shared__ alignas(16) short Ks[2][8192];   // [64 k][128 d] swizzled  (32KB)
  __shared__ alignas(16) short Vs[2][8192];   // [128 d][64 k] swizzled  (32KB)
  __shared__ alignas(16) short Ps[4][1024];   // per-wave [16 q][64 k] swizzled (8KB)

  int bid = blockIdx.x;
  int wg = (bid & 7) * 64 + (bid >> 3);       // same-bh blocks land on one XCD
  int bh = wg >> 4, qb = wg & 15;
  int b = bh >> 3, h = bh & 7;
  int tid = threadIdx.x, w = tid >> 6, lane = tid & 63, lo = lane & 15, hi = lane >> 4;
  int q0 = qb * 64 + w * 16;
  int q = q0 + lo;

  // Q fragments: lane holds Q[q][dk = kf*32 + hi*8 + i]
  s16x8 qfr[4];
#pragma unroll
  for (int kf = 0; kf < 4; ++kf)
    qfr[kf] = *(const s16x8*)(Qp + (size_t)(b * NQL + q) * CC + h * DHD + kf * 32 + hi * 8);

  f32x4 acc[8] = {};
  float m_ = -3e38f;
  float l_ = 0.f;

  int krow = lane >> 4;            // 0..3   (K: 16 lanes/row of 256B)
  int kcolb = (lane & 15) * 16;
  int vrow = lane >> 3;            // 0..7   (V: 8 lanes/row of 128B)
  int vcolb = (lane & 7) * 16;

  auto stage = [&](int t, int buf) {
    int kv0 = t * 64;
#pragma unroll
    for (int i = 0; i < 4; ++i) {
      int c = w * 4 + i;
      int row = c * 4 + krow;
      int sc = kcolb ^ ((row & 7) << 4);
      gld16(Kp + (size_t)(b * HWK + kv0 + row) * CC + h * DHD + (sc >> 1), (char*)Ks[buf] + c * 1024);
    }
#pragma unroll
    for (int i = 0; i < 4; ++i) {
      int c = w * 4 + i;
      int d = c * 8 + vrow;
      int sc = vcolb ^ ((d & 7) << 4);
      gld16(VT + (size_t)((b * NH + h) * DHD + d) * HWK + kv0 + (sc >> 1), (char*)Vs[buf] + c * 1024);
    }
  };

  stage(0, 0);
  __syncthreads();

  for (int t = 0; t < 64; ++t) {
    int buf = t & 1;
    if (t < 63) stage(t + 1, buf ^ 1);   // prefetch: drains at end-of-iter barrier

    // ---- S^T = K @ Q^T ----
    __builtin_amdgcn_s_setprio(1);
    f32x4 st[4] = {};
#pragma unroll
    for (int nf = 0; nf < 4; ++nf) {
      int kidx = nf * 16 + lo;
      int swz = (kidx & 7) << 4;
#pragma unroll
      for (int kf = 0; kf < 4; ++kf) {
        s16x8 a = *(const s16x8*)((const char*)Ks[buf] + kidx * 256 + ((kf * 64 + hi * 16) ^ swz));
        st[nf] = MFMA16(a, qfr[kf], st[nf]);
      }
    }
    __builtin_amdgcn_s_setprio(0);

    // ---- online softmax (wave-parallel; state per q=lane&15, replicated over hi) ----
    u64 word = Mb[(size_t)(b * NQL + q) * 64 + t];
    u32 halfm = (u32)(word >> (hi * 16)) & 0xFFFFu;
    float smax = -3e38f;
#pragma unroll
    for (int nf = 0; nf < 4; ++nf)
#pragma unroll
      for (int r = 0; r < 4; ++r) smax = fmaxf(smax, st[nf][r]);
    smax = fmaxf(smax, __shfl_xor(smax, 16));
    smax = fmaxf(smax, __shfl_xor(smax, 32));

    if (__any(smax > m_ + 8.f)) {        // defer-rescale: rarely taken after warm-up
      float mnew = fmaxf(m_, smax);
      float alpha = __builtin_amdgcn_exp2f(m_ - mnew);
      l_ *= alpha;
      m_ = mnew;
      float ar0 = __shfl(alpha, hi * 4 + 0);
      float ar1 = __shfl(alpha, hi * 4 + 1);
      float ar2 = __shfl(alpha, hi * 4 + 2);
      float ar3 = __shfl(alpha, hi * 4 + 3);
#pragma unroll
      for (int df = 0; df < 8; ++df) {
        acc[df][0] *= ar0; acc[df][1] *= ar1;
        acc[df][2] *= ar2; acc[df][3] *= ar3;
      }
    }

    float tsum = 0.f;
#pragma unroll
    for (int nf = 0; nf < 4; ++nf) {
      float p0 = __builtin_amdgcn_exp2f(st[nf][0] - m_);
      float p1 = __builtin_amdgcn_exp2f(st[nf][1] - m_);
      float p2 = __builtin_amdgcn_exp2f(st[nf][2] - m_);
      float p3 = __builtin_amdgcn_exp2f(st[nf][3] - m_);
      p0 = ((halfm >> (nf * 4 + 0)) & 1) ? p0 : 0.f;
      p1 = ((halfm >> (nf * 4 + 1)) & 1) ? p1 : 0.f;
      p2 = ((halfm >> (nf * 4 + 2)) & 1) ? p2 : 0.f;
      p3 = ((halfm >> (nf * 4 + 3)) & 1) ? p3 : 0.f;
      tsum += p0 + p1 + p2 + p3;
      u32 w0 = __builtin_amdgcn_perm(__float_as_uint(p1), __float_as_uint(p0), 0x07060302u);
      u32 w1 = __builtin_amdgcn_perm(__float_as_uint(p3), __float_as_uint(p2), 0x07060302u);
      uint2 pv; pv.x = w0; pv.y = w1;
      *(uint2*)((char*)Ps[w] + lo * 128 + ((nf * 32 + hi * 8) ^ ((lo & 7) << 4))) = pv;
    }
    tsum += __shfl_xor(tsum, 16);
    tsum += __shfl_xor(tsum, 32);
    l_ += tsum;
    asm volatile("" ::: "memory");   // keep P ds_writes before P ds_reads (alias fence)

    // ---- PV: acc[d] += P @ V ----
    __builtin_amdgcn_s_setprio(1);
#pragma unroll
    for (int kt = 0; kt < 2; ++kt) {
      s16x8 pa = *(const s16x8*)((const char*)Ps[w] + lo * 128 + ((kt * 64 + hi * 16) ^ ((lo & 7) << 4)));
#pragma unroll
      for (int df = 0; df < 8; ++df) {
        int d = df * 16 + lo;
        s16x8 vb = *(const s16x8*)((const char*)Vs[buf] + d * 128 + ((kt * 64 + hi * 16) ^ ((lo & 7) << 4)));
        acc[df] = MFMA16(pa, vb, acc[df]);
      }
    }
    __builtin_amdgcn_s_setprio(0);
    __syncthreads();
  }

  // ---- epilogue: out = acc / l -> bf16 AO[B,NQ,C] ----
  float linv = 1.0f / l_;
  float lr0 = __shfl(linv, hi * 4 + 0);
  float lr1 = __shfl(linv, hi * 4 + 1);
  float lr2 = __shfl(linv, hi * 4 + 2);
  float lr3 = __shfl(linv, hi * 4 + 3);
  int qbase = q0 + hi * 4;
#pragma unroll
  for (int df = 0; df < 8; ++df) {
    int col = h * DHD + df * 16 + lo;
    AO[(size_t)(b * NQL + qbase + 0) * CC + col] = (short)f2bf(acc[df][0] * lr0);
    AO[(size_t)(b * NQL + qbase + 1) * CC + col] = (short)f2bf(acc[df][1] * lr1);
    AO[(size_t)(b * NQL + qbase + 2) * CC + col] = (short)f2bf(acc[df][2] * lr2);
    AO[(size_t)(b * NQL + qbase + 3) * CC + col] = (short)f2bf(acc[df][3] * lr3);
  }
}

// ---------------- launcher ----------------
extern "C" void kernel_launch(void* const* d_in, const int* in_sizes, int n_in,
                              void* d_out, int out_size, void* d_ws, size_t ws_size,
                              hipStream_t stream) {
  (void)in_sizes; (void)n_in; (void)out_size; (void)ws_size;
  const float* query = (const float*)d_in[0];
  const float* memory = (const float*)d_in[1];
  const float* mask = (const float*)d_in[2];
  const float* Wq = (const float*)d_in[3];
  const float* bq = (const float*)d_in[4];
  const float* Wk = (const float*)d_in[5];
  const float* bk = (const float*)d_in[6];
  const float* Wv = (const float*)d_in[7];
  const float* bv = (const float*)d_in[8];
  const float* Wo = (const float*)d_in[9];
  const float* bo = (const float*)d_in[10];
  float* out = (float*)d_out;

  char* ws = (char*)d_ws;
  short* qbf = (short*)(ws);                      // 8MB  query bf16
  short* mbf = (short*)(ws + (8ull << 20));       // 32MB memory bf16
  short* wqb = (short*)(ws + (40ull << 20));      // 2MB each: Wq,Wk,Wv,Wo bf16
  short* wkb = wqb + (1u << 20);
  short* wvb = wqb + (2u << 20);
  short* wob = wqb + (3u << 20);
  u64* mbits = (u64*)(ws + (48ull << 20));        // 2MB mask bits
  short* Qp = (short*)(ws + (50ull << 20));       // 8MB  Q proj  [B,NQ,C]
  short* Kp = (short*)(ws + (58ull << 20));       // 32MB K proj  [B,HW,C]
  short* VT = (short*)(ws + (90ull << 20));       // 32MB V proj  [B,H,DH,HW]
  short* AO = (short*)(ws + (122ull << 20));      // 8MB  attn out [B,NQ,C]

  cvt_bf16<<<2048, 256, 0, stream>>>(query, qbf, (NB * NQL * CC) / 8);
  cvt_bf16<<<2048, 256, 0, stream>>>(memory, mbf, (NB * HWK * CC) / 8);
  cvt_bf16<<<512, 256, 0, stream>>>(Wq, wqb, (CC * CC) / 8);
  cvt_bf16<<<512, 256, 0, stream>>>(Wk, wkb, (CC * CC) / 8);
  cvt_bf16<<<512, 256, 0, stream>>>(Wv, wvb, (CC * CC) / 8);
  cvt_bf16<<<512, 256, 0, stream>>>(Wo, wob, (CC * CC) / 8);
  mask_bits<<<65536, 256, 0, stream>>>(mask, mbits);

  const float qscale = 0.08838834764831845f * 1.4426950408889634f;  // 1/sqrt(128) * log2(e)
  gemm_bt<0><<<256, 256, 0, stream>>>(qbf, wqb, bq, Qp, qscale);
  gemm_bt<1><<<1024, 256, 0, stream>>>(mbf, wkb, bk, Kp, 1.0f);
  gemm_bt<2><<<1024, 256, 0, stream>>>(mbf, wvb, bv, VT, 1.0f);
  attn_kernel<<<512, 256, 0, stream>>>(Qp, Kp, VT, mbits, AO);
  gemm_bt<3><<<256, 256, 0, stream>>>(AO, wob, bo, out, 1.0f);
}

// Round 3
// 451.933 us; speedup vs baseline: 1.1620x; 1.0166x over previous
//
#include <hip/hip_runtime.h>

// MaskedAttention: B=4, NQ=1024, HW=4096, C=1024, H=8, DH=128
// Pipeline: cvt(f32->bf16) -> maskbits -> GEMM Q/K/V (bf16 MFMA) -> flash attn -> GEMM O (f32 out)

#define NB 4
#define NQL 1024
#define HWK 4096
#define CC 1024
#define NH 8
#define DHD 128

typedef __attribute__((ext_vector_type(8))) short s16x8;
typedef __attribute__((ext_vector_type(4))) short s16x4;
typedef __attribute__((ext_vector_type(4))) float f32x4;
typedef unsigned int u32;
typedef unsigned long long u64;
typedef const __attribute__((address_space(1))) u32* gas1;
typedef __attribute__((address_space(3))) u32* las3;

__device__ __forceinline__ unsigned short f2bf(float f) {
  u32 u = __float_as_uint(f);
  u32 r = u + 0x7FFFu + ((u >> 16) & 1u);   // RNE
  return (unsigned short)(r >> 16);
}

__device__ __forceinline__ void gld16(const void* g, void* l) {
  __builtin_amdgcn_global_load_lds((gas1)g, (las3)l, 16, 0, 0);
}

#define MFMA16(a, b, c) __builtin_amdgcn_mfma_f32_16x16x32_bf16((a), (b), (c), 0, 0, 0)

// ---------------- f32 -> bf16 (RNE), 8 elems/thread ----------------
__global__ void cvt_bf16(const float* __restrict__ s, short* __restrict__ d, int n8) {
  int i = blockIdx.x * 256 + threadIdx.x;
  int stride = gridDim.x * 256;
  for (; i < n8; i += stride) {
    const float4* s4 = (const float4*)s;
    float4 a = s4[i * 2];
    float4 b = s4[i * 2 + 1];
    s16x8 o;
    o[0] = (short)f2bf(a.x); o[1] = (short)f2bf(a.y);
    o[2] = (short)f2bf(a.z); o[3] = (short)f2bf(a.w);
    o[4] = (short)f2bf(b.x); o[5] = (short)f2bf(b.y);
    o[6] = (short)f2bf(b.z); o[7] = (short)f2bf(b.w);
    *(s16x8*)(d + (size_t)i * 8) = o;
  }
}

// 4 weight matrices (1M elems each) in one launch; block range selects matrix (uniform per block)
__global__ void cvt_w4(const float* s0, const float* s1, const float* s2, const float* s3,
                       short* d0, short* d1, short* d2, short* d3) {
  int bb = blockIdx.x;
  int si = bb >> 9;
  const float* s = si == 0 ? s0 : si == 1 ? s1 : si == 2 ? s2 : s3;
  short* d = si == 0 ? d0 : si == 1 ? d1 : si == 2 ? d2 : d3;
  int i = (bb & 511) * 256 + threadIdx.x;
  const float4* s4 = (const float4*)s;
  float4 a = s4[i * 2];
  float4 b = s4[i * 2 + 1];
  s16x8 o;
  o[0] = (short)f2bf(a.x); o[1] = (short)f2bf(a.y);
  o[2] = (short)f2bf(a.z); o[3] = (short)f2bf(a.w);
  o[4] = (short)f2bf(b.x); o[5] = (short)f2bf(b.y);
  o[6] = (short)f2bf(b.z); o[7] = (short)f2bf(b.w);
  *(s16x8*)(d + (size_t)i * 8) = o;
}

// ---------------- mask -> bitmask words, natural bit order ----------------
// layout: words[((b*16 + (q>>6))*64 + t)*64 + (q&63)], bit k of word = allowed(kv = t*64+k)
__global__ void mask_bits(const float* __restrict__ mask, u64* __restrict__ words) {
  int gw = (blockIdx.x * 256 + threadIdx.x) >> 6;
  int lane = threadIdx.x & 63;
  int nw = (gridDim.x * 256) >> 6;
  for (int wi = gw; wi < 262144; wi += nw) {
    int ql = wi & 63;
    int t = (wi >> 6) & 63;
    int qh = (wi >> 12) & 15;
    int bb = wi >> 16;
    size_t src = ((size_t)((bb << 10) + (qh << 6) + ql) << 12) + t * 64 + lane;
    u64 bits = __ballot(mask[src] >= 0.5f);
    if (lane == 0) words[wi] = bits;
  }
}

// ---------------- GEMM: C[M,N] = A[M,K] @ W[N,K]^T + bias ; N=K=1024 ----------------
// 128x128 tile, BK=32, 4 waves. T3-minimum 2-phase: double-buffered LDS, prefetch(t+1)
// issued BEFORE compute(t), ONE barrier per K-step (load latency hidden under MFMA).
// EPI: 0 = bf16 out, (acc+bias)*scale   (Q-proj, scale folds 1/sqrt(dh)*log2e)
//      1 = bf16 out, acc+bias           (K-proj)
//      2 = bf16 out transposed to [B,H,DH,HW]  (V-proj)
//      3 = f32 out, acc+bias            (O-proj -> d_out)
template <int EPI>
__global__ __launch_bounds__(256, 3) void gemm_bt(const short* __restrict__ A,
                                                  const short* __restrict__ W,
                                                  const float* __restrict__ bias,
                                                  void* __restrict__ Cout, float scale) {
  __shared__ alignas(16) short As[2][4096];
  __shared__ alignas(16) short Bs[2][4096];
  int nwg = gridDim.x;
  int bid = blockIdx.x;
  int wg = (bid & 7) * (nwg >> 3) + (bid >> 3);   // bijective XCD swizzle (nwg%8==0)
  int bm = wg >> 3;
  int bn = wg & 7;
  int tid = threadIdx.x;
  int w = tid >> 6, lane = tid & 63, lo = lane & 15, hi = lane >> 4;
  int wr = w >> 1, wc = w & 1;
  const short* Ab = A + (size_t)bm * 128 * 1024;
  const short* Wb = W + (size_t)bn * 128 * 1024;
  f32x4 acc[4][4] = {};
  int srow = lane >> 2;             // row within 16-row chunk
  int scolb = (lane & 3) * 16;      // byte col within 64B row

  // per-lane staging base pointers (pre-swizzled source, linear LDS dest)
  const short* asrc[2];
  const short* bsrc[2];
#pragma unroll
  for (int i = 0; i < 2; ++i) {
    int c = w * 2 + i;
    int row = c * 16 + srow;
    int sc = scolb ^ ((row & 3) << 4);
    asrc[i] = Ab + (size_t)row * 1024 + (sc >> 1);
    bsrc[i] = Wb + (size_t)row * 1024 + (sc >> 1);
  }

  auto stage = [&](int kt, int bufi) {
#pragma unroll
    for (int i = 0; i < 2; ++i) {
      int c = w * 2 + i;
      gld16(asrc[i] + kt * 32, (char*)As[bufi] + c * 1024);
      gld16(bsrc[i] + kt * 32, (char*)Bs[bufi] + c * 1024);
    }
  };

  stage(0, 0);
  __syncthreads();
  int buf = 0;
  for (int kt = 0; kt < 32; ++kt) {
    if (kt < 31) stage(kt + 1, buf ^ 1);   // in flight during MFMA; drains at barrier
    s16x8 af[4], bf[4];
#pragma unroll
    for (int mf = 0; mf < 4; ++mf) {
      int row = wr * 64 + mf * 16 + lo;
      af[mf] = *(const s16x8*)((const char*)As[buf] + row * 64 + ((hi * 16) ^ ((row & 3) << 4)));
    }
#pragma unroll
    for (int nf = 0; nf < 4; ++nf) {
      int row = wc * 64 + nf * 16 + lo;
      bf[nf] = *(const s16x8*)((const char*)Bs[buf] + row * 64 + ((hi * 16) ^ ((row & 3) << 4)));
    }
#pragma unroll
    for (int mf = 0; mf < 4; ++mf)
#pragma unroll
      for (int nf = 0; nf < 4; ++nf) acc[mf][nf] = MFMA16(af[mf], bf[nf], acc[mf][nf]);
    __syncthreads();
    buf ^= 1;
  }

  // epilogue: C/D layout col=lane&15, row=(lane>>4)*4+reg
#pragma unroll
  for (int nf = 0; nf < 4; ++nf) {
    int n = bn * 128 + wc * 64 + nf * 16 + lo;
    float bv = bias[n];
#pragma unroll
    for (int mf = 0; mf < 4; ++mf) {
      int m0 = bm * 128 + wr * 64 + mf * 16 + hi * 4;
      if constexpr (EPI == 0 || EPI == 1) {
        short* O = (short*)Cout;
#pragma unroll
        for (int r = 0; r < 4; ++r) {
          float v = acc[mf][nf][r] + bv;
          if constexpr (EPI == 0) v *= scale;
          O[(size_t)(m0 + r) * 1024 + n] = (short)f2bf(v);
        }
      } else if constexpr (EPI == 2) {
        short* O = (short*)Cout;
        int bb = m0 >> 12;       // batch (HW=4096 rows per batch)
        int kk = m0 & 4095;      // key index
        s16x4 pk;
#pragma unroll
        for (int r = 0; r < 4; ++r) pk[r] = (short)f2bf(acc[mf][nf][r] + bv);
        *(s16x4*)(O + (size_t)bb * 4194304 + (size_t)n * 4096 + kk) = pk;
      } else {
        float* O = (float*)Cout;
#pragma unroll
        for (int r = 0; r < 4; ++r) O[(size_t)(m0 + r) * 1024 + n] = acc[mf][nf][r] + bv;
      }
    }
  }
}

// ---------------- flash attention ----------------
// grid 512: wg = bh*16 + qb (XCD-swizzled). Block = 4 waves, each owns 16 q-rows; 2 blocks/CU.
// KVBLK=64, K/V double-buffered LDS (XOR swizzle via pre-swizzled global src).
// Swapped QK^T: S^T = mfma(K_frag, Q_frag) -> lane holds S^T[k][q=lane&15].
// Q pre-scaled by (1/sqrt(128))*log2e so softmax = exp2. Defer-rescale THR=8.
__global__ __launch_bounds__(256, 2) void attn_kernel(const short* __restrict__ Qp,
                                                      const short* __restrict__ Kp,
                                                      const short* __restrict__ VT,
                                                      const u64* __restrict__ Mb,
                                                      short* __restrict__ AO) {
  __shared__ alignas(16) short Ks[2][8192];   // [64 k][128 d] swizzled  (32KB)
  __shared__ alignas(16) short Vs[2][8192];   // [128 d][64 k] swizzled  (32KB)
  __shared__ alignas(16) short Ps[4][1024];   // per-wave [16 q][64 k] swizzled (8KB)

  int bid = blockIdx.x;
  int wg = (bid & 7) * 64 + (bid >> 3);       // same-bh blocks land on one XCD
  int bh = wg >> 4, qb = wg & 15;
  int b = bh >> 3, h = bh & 7;
  int tid = threadIdx.x, w = tid >> 6, lane = tid & 63, lo = lane & 15, hi = lane >> 4;
  int q0 = qb * 64 + w * 16;
  int q = q0 + lo;

  // Q fragments: lane holds Q[q][dk = kf*32 + hi*8 + i]
  s16x8 qfr[4];
#pragma unroll
  for (int kf = 0; kf < 4; ++kf)
    qfr[kf] = *(const s16x8*)(Qp + (size_t)(b * NQL + q) * CC + h * DHD + kf * 32 + hi * 8);

  f32x4 acc[8] = {};
  float m_ = -3e38f;
  float l_ = 0.f;

  int krow = lane >> 4;            // 0..3   (K: 16 lanes/row of 256B)
  int kcolb = (lane & 15) * 16;
  int vrow = lane >> 3;            // 0..7   (V: 8 lanes/row of 128B)
  int vcolb = (lane & 7) * 16;

  // hoisted per-lane staging base pointers; tile t adds t<<16 (K) / t<<6 (V) shorts
  const short* kbase[4];
  const short* vbase[4];
#pragma unroll
  for (int i = 0; i < 4; ++i) {
    int c = w * 4 + i;
    int row = c * 4 + krow;
    int sc = kcolb ^ ((row & 7) << 4);
    kbase[i] = Kp + (size_t)(b * HWK + row) * CC + h * DHD + (sc >> 1);
    int d = c * 8 + vrow;
    int scv = vcolb ^ ((d & 7) << 4);
    vbase[i] = VT + (size_t)((b * NH + h) * DHD + d) * HWK + (scv >> 1);
  }
  // coalesced mask pointer: [b][qb][t][q&63]; this wave reads 16 consecutive words per tile
  const u64* mp = Mb + ((size_t)(b * 16 + qb) << 12) + (w * 16 + lo);

  auto stage = [&](int t, int bufi) {
#pragma unroll
    for (int i = 0; i < 4; ++i)
      gld16(kbase[i] + ((size_t)t << 16), (char*)Ks[bufi] + (w * 4 + i) * 1024);
#pragma unroll
    for (int i = 0; i < 4; ++i)
      gld16(vbase[i] + ((size_t)t << 6), (char*)Vs[bufi] + (w * 4 + i) * 1024);
  };

  stage(0, 0);
  __syncthreads();

  for (int t = 0; t < 64; ++t) {
    int buf = t & 1;
    u64 word = mp[(size_t)t << 6];       // issue early: L2 latency hides under QK^T
    if (t < 63) stage(t + 1, buf ^ 1);   // prefetch: drains at end-of-iter barrier

    // ---- S^T = K @ Q^T ----
    __builtin_amdgcn_s_setprio(1);
    f32x4 st[4] = {};
#pragma unroll
    for (int nf = 0; nf < 4; ++nf) {
      int kidx = nf * 16 + lo;
      int swz = (kidx & 7) << 4;
#pragma unroll
      for (int kf = 0; kf < 4; ++kf) {
        s16x8 a = *(const s16x8*)((const char*)Ks[buf] + kidx * 256 + ((kf * 64 + hi * 16) ^ swz));
        st[nf] = MFMA16(a, qfr[kf], st[nf]);
      }
    }
    __builtin_amdgcn_s_setprio(0);

    // ---- online softmax (state per q=lane&15, replicated over hi) ----
    u64 sh = word >> (hi * 4);
    u32 mlo32 = (u32)sh, mhi32 = (u32)(sh >> 32);
    float smax = -3e38f;
#pragma unroll
    for (int nf = 0; nf < 4; ++nf)
#pragma unroll
      for (int r = 0; r < 4; ++r) smax = fmaxf(smax, st[nf][r]);
    smax = fmaxf(smax, __shfl_xor(smax, 16));
    smax = fmaxf(smax, __shfl_xor(smax, 32));

    if (__any(smax > m_ + 8.f)) {        // defer-rescale: rarely taken after warm-up
      float mnew = fmaxf(m_, smax);
      float alpha = __builtin_amdgcn_exp2f(m_ - mnew);
      l_ *= alpha;
      m_ = mnew;
      float ar0 = __shfl(alpha, hi * 4 + 0);
      float ar1 = __shfl(alpha, hi * 4 + 1);
      float ar2 = __shfl(alpha, hi * 4 + 2);
      float ar3 = __shfl(alpha, hi * 4 + 3);
#pragma unroll
      for (int df = 0; df < 8; ++df) {
        acc[df][0] *= ar0; acc[df][1] *= ar1;
        acc[df][2] *= ar2; acc[df][3] *= ar3;
      }
    }

    float tsum = 0.f;
#pragma unroll
    for (int nf = 0; nf < 4; ++nf) {
      u32 mx = (nf < 2) ? mlo32 : mhi32;
      int bs = (nf & 1) * 16;
      float p0 = __builtin_amdgcn_exp2f(st[nf][0] - m_);
      float p1 = __builtin_amdgcn_exp2f(st[nf][1] - m_);
      float p2 = __builtin_amdgcn_exp2f(st[nf][2] - m_);
      float p3 = __builtin_amdgcn_exp2f(st[nf][3] - m_);
      p0 = ((mx >> (bs + 0)) & 1) ? p0 : 0.f;
      p1 = ((mx >> (bs + 1)) & 1) ? p1 : 0.f;
      p2 = ((mx >> (bs + 2)) & 1) ? p2 : 0.f;
      p3 = ((mx >> (bs + 3)) & 1) ? p3 : 0.f;
      tsum += p0 + p1 + p2 + p3;
      u32 w0 = __builtin_amdgcn_perm(__float_as_uint(p1), __float_as_uint(p0), 0x07060302u);
      u32 w1 = __builtin_amdgcn_perm(__float_as_uint(p3), __float_as_uint(p2), 0x07060302u);
      uint2 pv; pv.x = w0; pv.y = w1;
      *(uint2*)((char*)Ps[w] + lo * 128 + ((nf * 32 + hi * 8) ^ ((lo & 7) << 4))) = pv;
    }
    tsum += __shfl_xor(tsum, 16);
    tsum += __shfl_xor(tsum, 32);
    l_ += tsum;
    asm volatile("" ::: "memory");   // keep P ds_writes before P ds_reads (alias fence)

    // ---- PV: acc[d] += P @ V ----
    __builtin_amdgcn_s_setprio(1);
#pragma unroll
    for (int kt = 0; kt < 2; ++kt) {
      s16x8 pa = *(const s16x8*)((const char*)Ps[w] + lo * 128 + ((kt * 64 + hi * 16) ^ ((lo & 7) << 4)));
#pragma unroll
      for (int df = 0; df < 8; ++df) {
        int d = df * 16 + lo;
        s16x8 vb = *(const s16x8*)((const char*)Vs[buf] + d * 128 + ((kt * 64 + hi * 16) ^ ((lo & 7) << 4)));
        acc[df] = MFMA16(pa, vb, acc[df]);
      }
    }
    __builtin_amdgcn_s_setprio(0);
    __syncthreads();
  }

  // ---- epilogue: out = acc / l -> bf16 AO[B,NQ,C] ----
  float linv = 1.0f / l_;
  float lr0 = __shfl(linv, hi * 4 + 0);
  float lr1 = __shfl(linv, hi * 4 + 1);
  float lr2 = __shfl(linv, hi * 4 + 2);
  float lr3 = __shfl(linv, hi * 4 + 3);
  int qbase = q0 + hi * 4;
#pragma unroll
  for (int df = 0; df < 8; ++df) {
    int col = h * DHD + df * 16 + lo;
    AO[(size_t)(b * NQL + qbase + 0) * CC + col] = (short)f2bf(acc[df][0] * lr0);
    AO[(size_t)(b * NQL + qbase + 1) * CC + col] = (short)f2bf(acc[df][1] * lr1);
    AO[(size_t)(b * NQL + qbase + 2) * CC + col] = (short)f2bf(acc[df][2] * lr2);
    AO[(size_t)(b * NQL + qbase + 3) * CC + col] = (short)f2bf(acc[df][3] * lr3);
  }
}

// ---------------- launcher ----------------
extern "C" void kernel_launch(void* const* d_in, const int* in_sizes, int n_in,
                              void* d_out, int out_size, void* d_ws, size_t ws_size,
                              hipStream_t stream) {
  (void)in_sizes; (void)n_in; (void)out_size; (void)ws_size;
  const float* query = (const float*)d_in[0];
  const float* memory = (const float*)d_in[1];
  const float* mask = (const float*)d_in[2];
  const float* Wq = (const float*)d_in[3];
  const float* bq = (const float*)d_in[4];
  const float* Wk = (const float*)d_in[5];
  const float* bk = (const float*)d_in[6];
  const float* Wv = (const float*)d_in[7];
  const float* bv = (const float*)d_in[8];
  const float* Wo = (const float*)d_in[9];
  const float* bo = (const float*)d_in[10];
  float* out = (float*)d_out;

  char* ws = (char*)d_ws;
  short* qbf = (short*)(ws);                      // 8MB  query bf16
  short* mbf = (short*)(ws + (8ull << 20));       // 32MB memory bf16
  short* wqb = (short*)(ws + (40ull << 20));      // 2MB each: Wq,Wk,Wv,Wo bf16
  short* wkb = wqb + (1u << 20);
  short* wvb = wqb + (2u << 20);
  short* wob = wqb + (3u << 20);
  u64* mbits = (u64*)(ws + (48ull << 20));        // 2MB mask bits
  short* Qp = (short*)(ws + (50ull << 20));       // 8MB  Q proj  [B,NQ,C]
  short* Kp = (short*)(ws + (58ull << 20));       // 32MB K proj  [B,HW,C]
  short* VT = (short*)(ws + (90ull << 20));       // 32MB V proj  [B,H,DH,HW]
  short* AO = (short*)(ws + (122ull << 20));      // 8MB  attn out [B,NQ,C]

  cvt_bf16<<<2048, 256, 0, stream>>>(query, qbf, (NB * NQL * CC) / 8);
  cvt_bf16<<<2048, 256, 0, stream>>>(memory, mbf, (NB * HWK * CC) / 8);
  cvt_w4<<<2048, 256, 0, stream>>>(Wq, Wk, Wv, Wo, wqb, wkb, wvb, wob);
  mask_bits<<<4096, 256, 0, stream>>>(mask, mbits);

  const float qscale = 0.08838834764831845f * 1.4426950408889634f;  // 1/sqrt(128) * log2(e)
  gemm_bt<0><<<256, 256, 0, stream>>>(qbf, wqb, bq, Qp, qscale);
  gemm_bt<1><<<1024, 256, 0, stream>>>(mbf, wkb, bk, Kp, 1.0f);
  gemm_bt<2><<<1024, 256, 0, stream>>>(mbf, wvb, bv, VT, 1.0f);
  attn_kernel<<<512, 256, 0, stream>>>(Qp, Kp, VT, mbits, AO);
  gemm_bt<3><<<256, 256, 0, stream>>>(AO, wob, bo, out, 1.0f);
}